// Round 1
// baseline (1623.186 us; speedup 1.0000x reference)
//
#include <hip/hip_runtime.h>
#include <math.h>

#define T_PRED 30
#define BN 2048
#define DD 256
#define DHH 128

// ---- workspace layout (needs ~76 MB) ----
// [0]      : float nce_sum
// [8]      : int correct
// 4096     : pred  [T,B,D] f32          = 62,914,560 B
// then     : totals29 [B,B] f32         = 16,777,216 B
// then     : lse29 [B] f32              = 8,192 B
#define WS_PRED_OFF   4096
#define WS_PRED_BYTES ((size_t)T_PRED * BN * DD * 4)
#define WS_TOT_OFF    (WS_PRED_OFF + WS_PRED_BYTES)
#define WS_TOT_BYTES  ((size_t)BN * BN * 4)
#define WS_LSE_OFF    (WS_TOT_OFF + WS_TOT_BYTES)

// pred[t,c,d] = sum_h rep[c,h] * Wk_w[t,d,h] + Wk_b[t,d]
// 64x64 tile per block over DH=128. LDS rows padded to 132 (132%32==4 -> 2-way max).
__global__ __launch_bounds__(256) void pred_kernel(
    const float* __restrict__ rep, const float* __restrict__ Ww,
    const float* __restrict__ Wb, float* __restrict__ pred)
{
    __shared__ float rep_s[64 * 132];
    __shared__ float w_s[64 * 132];
    const int t  = blockIdx.z;
    const int c0 = blockIdx.y * 64;
    const int d0 = blockIdx.x * 64;
    const int tid = threadIdx.x;
    const int tx = tid & 15, ty = tid >> 4;

    // stage: 64 rows x 128 floats each = 2048 float4 per array, 8 per thread
    for (int it = 0; it < 8; ++it) {
        int idx = tid + it * 256;       // float4 index
        int row = idx >> 5;             // 32 float4 per row
        int off = (idx & 31) * 4;
        *(float4*)&rep_s[row * 132 + off] =
            *(const float4*)&rep[(size_t)(c0 + row) * DHH + off];
        *(float4*)&w_s[row * 132 + off] =
            *(const float4*)&Ww[((size_t)t * DD + d0 + row) * DHH + off];
    }
    __syncthreads();

    float acc[4][4] = {};
    for (int k = 0; k < DHH; k += 4) {
        float4 e[4], p[4];
#pragma unroll
        for (int i = 0; i < 4; ++i) e[i] = *(const float4*)&rep_s[(i * 16 + ty) * 132 + k];
#pragma unroll
        for (int j = 0; j < 4; ++j) p[j] = *(const float4*)&w_s[(j * 16 + tx) * 132 + k];
#pragma unroll
        for (int i = 0; i < 4; ++i)
#pragma unroll
            for (int j = 0; j < 4; ++j) {
                acc[i][j] = fmaf(e[i].x, p[j].x, acc[i][j]);
                acc[i][j] = fmaf(e[i].y, p[j].y, acc[i][j]);
                acc[i][j] = fmaf(e[i].z, p[j].z, acc[i][j]);
                acc[i][j] = fmaf(e[i].w, p[j].w, acc[i][j]);
            }
    }

#pragma unroll
    for (int j = 0; j < 4; ++j) {
        float bj = Wb[(size_t)t * DD + d0 + j * 16 + tx];
#pragma unroll
        for (int i = 0; i < 4; ++i) {
            pred[((size_t)t * BN + c0 + i * 16 + ty) * DD + d0 + j * 16 + tx] =
                acc[i][j] + bj;
        }
    }
}

// Fused totals GEMM + online row softmax (over c) + diag capture.
// Block: t = blockIdx.y, rows row0..row0+63. Loops over 32 col-tiles of 64.
// LDS rows padded to 260 (260%32==4 -> 2-way max; 260*4 bytes is 16B aligned).
__global__ __launch_bounds__(256) void nce_kernel(
    const float* __restrict__ E, const float* __restrict__ P,
    float* __restrict__ nce_acc, float* __restrict__ tot29,
    float* __restrict__ lse29)
{
    __shared__ float e_s[64 * 260];
    __shared__ float p_s[64 * 260];
    __shared__ float red_s[16];
    const int t    = blockIdx.y;
    const int row0 = blockIdx.x * 64;
    const int tid  = threadIdx.x;
    const int tx = tid & 15, ty = tid >> 4;
    const bool last = (t == T_PRED - 1);

    // stage E rows once: 64 rows x 256 floats = 4096 float4, 16 per thread
    for (int it = 0; it < 16; ++it) {
        int idx = tid + it * 256;
        int row = idx >> 6;             // 64 float4 per row
        int off = (idx & 63) * 4;
        *(float4*)&e_s[row * 260 + off] =
            *(const float4*)&E[((size_t)t * BN + row0 + row) * DD + off];
    }

    float m[4], s[4], dsum[4];
#pragma unroll
    for (int i = 0; i < 4; ++i) { m[i] = -3.4e38f; s[i] = 0.f; dsum[i] = 0.f; }

    for (int c0 = 0; c0 < BN; c0 += 64) {
        __syncthreads();  // also covers initial E staging
        for (int it = 0; it < 16; ++it) {
            int idx = tid + it * 256;
            int row = idx >> 6;
            int off = (idx & 63) * 4;
            *(float4*)&p_s[row * 260 + off] =
                *(const float4*)&P[((size_t)t * BN + c0 + row) * DD + off];
        }
        __syncthreads();

        float acc[4][4] = {};
        for (int k = 0; k < DD; k += 4) {
            float4 e[4], p[4];
#pragma unroll
            for (int i = 0; i < 4; ++i) e[i] = *(const float4*)&e_s[(i * 16 + ty) * 260 + k];
#pragma unroll
            for (int j = 0; j < 4; ++j) p[j] = *(const float4*)&p_s[(j * 16 + tx) * 260 + k];
#pragma unroll
            for (int i = 0; i < 4; ++i)
#pragma unroll
                for (int j = 0; j < 4; ++j) {
                    acc[i][j] = fmaf(e[i].x, p[j].x, acc[i][j]);
                    acc[i][j] = fmaf(e[i].y, p[j].y, acc[i][j]);
                    acc[i][j] = fmaf(e[i].z, p[j].z, acc[i][j]);
                    acc[i][j] = fmaf(e[i].w, p[j].w, acc[i][j]);
                }
        }

        // diag capture + last-step spill
#pragma unroll
        for (int i = 0; i < 4; ++i) {
            int rr = row0 + i * 16 + ty;
#pragma unroll
            for (int j = 0; j < 4; ++j) {
                int cc = c0 + j * 16 + tx;
                if (cc == rr) dsum[i] += acc[i][j];
                if (last) tot29[(size_t)rr * BN + cc] = acc[i][j];
            }
        }

        // online softmax update per row (16 lanes with same ty share a row)
#pragma unroll
        for (int i = 0; i < 4; ++i) {
            float tmax = acc[i][0];
#pragma unroll
            for (int j = 1; j < 4; ++j) tmax = fmaxf(tmax, acc[i][j]);
            for (int o = 1; o < 16; o <<= 1) tmax = fmaxf(tmax, __shfl_xor(tmax, o, 64));
            float mn = fmaxf(m[i], tmax);
            float ps = 0.f;
#pragma unroll
            for (int j = 0; j < 4; ++j) ps += __expf(acc[i][j] - mn);
            for (int o = 1; o < 16; o <<= 1) ps += __shfl_xor(ps, o, 64);
            s[i] = s[i] * __expf(m[i] - mn) + ps;
            m[i] = mn;
        }
    }

    float contrib = 0.f;
#pragma unroll
    for (int i = 0; i < 4; ++i) {
        float dtot = dsum[i];
        for (int o = 1; o < 16; o <<= 1) dtot += __shfl_xor(dtot, o, 64);
        float lse = m[i] + __logf(s[i]);
        if (tx == 0) {
            contrib += lse - dtot;
            if (last) lse29[row0 + i * 16 + ty] = lse;
        }
    }
    if (tx == 0) red_s[ty] = contrib;
    __syncthreads();
    if (tid == 0) {
        float bs = 0.f;
        for (int q = 0; q < 16; ++q) bs += red_s[q];
        atomicAdd(nce_acc, bs);
    }
}

// For each column c: argmax over b of (tot29[b,c] - lse29[b]); count arg==c.
__global__ __launch_bounds__(256) void acc_kernel(
    const float* __restrict__ tot29, const float* __restrict__ lse29,
    int* __restrict__ correct)
{
    int c = blockIdx.x * 256 + threadIdx.x;
    float best = -3.4e38f;
    int arg = -1;
    for (int b = 0; b < BN; ++b) {
        float v = tot29[(size_t)b * BN + c] - lse29[b];
        if (v > best) { best = v; arg = b; }   // strict > keeps first index on ties
    }
    if (arg == c) atomicAdd(correct, 1);
}

__global__ void fin_kernel(const float* __restrict__ nce_acc,
                           const int* __restrict__ correct,
                           float* __restrict__ out)
{
    if (threadIdx.x == 0) {
        out[0] = (float)(*correct) / (float)BN;
        out[1] = (*nce_acc) / (float)(BN * T_PRED);
        out[2] = (float)BN;
        out[3] = (float)(BN * T_PRED);
    }
}

extern "C" void kernel_launch(void* const* d_in, const int* in_sizes, int n_in,
                              void* d_out, int out_size, void* d_ws, size_t ws_size,
                              hipStream_t stream) {
    const float* E   = (const float*)d_in[0];   // [T,B,D]
    const float* rep = (const float*)d_in[1];   // [B,DH]
    const float* Ww  = (const float*)d_in[2];   // [T,D,DH]
    const float* Wb  = (const float*)d_in[3];   // [T,D]
    float* out = (float*)d_out;

    char* ws = (char*)d_ws;
    float* nce_acc = (float*)(ws + 0);
    int*   correct = (int*)(ws + 8);
    float* pred    = (float*)(ws + WS_PRED_OFF);
    float* tot29   = (float*)(ws + WS_TOT_OFF);
    float* lse29   = (float*)(ws + WS_LSE_OFF);

    hipMemsetAsync(ws, 0, 256, stream);
    pred_kernel<<<dim3(4, 32, 30), 256, 0, stream>>>(rep, Ww, Wb, pred);
    nce_kernel<<<dim3(32, 30), 256, 0, stream>>>(E, pred, nce_acc, tot29, lse29);
    acc_kernel<<<dim3(8), 256, 0, stream>>>(tot29, lse29, correct);
    fin_kernel<<<1, 64, 0, stream>>>(nce_acc, correct, out);
}

// Round 2
// 501.820 us; speedup vs baseline: 3.2346x; 3.2346x over previous
//
#include <hip/hip_runtime.h>
#include <math.h>

typedef unsigned short u16;
typedef unsigned int   u32;
typedef unsigned long long u64;

#define T_PRED 30
#define BN 2048
#define DD 256
#define DHH 128
#define BK 32

typedef __attribute__((ext_vector_type(8))) short short8;   // 8 x bf16
typedef __attribute__((ext_vector_type(4))) float f32x4;

// ---- workspace layout (~138 MB) ----
// 0       : float nce_acc ; 8: int correct
// 4096    : u64 argmax table[2048]            (16384 B)
// 20480   : float lse29[2048]                 (8192 B)
// 32768   : E_hi  u16[T*B*D]                  (31,457,280 B)
// + split : E_lo, P_hi, P_lo                  (same each)
// then    : tot29 f32[B*B]                    (16,777,216 B)
// then    : pred29 f32[B*D]                   (2,097,152 B)
#define WS_ARG_OFF    4096
#define WS_LSE_OFF    20480
#define WS_EH_OFF     32768
#define WS_SPLIT_B    ((size_t)T_PRED * BN * DD * 2)
#define WS_EL_OFF     (WS_EH_OFF + WS_SPLIT_B)
#define WS_PH_OFF     (WS_EL_OFF + WS_SPLIT_B)
#define WS_PL_OFF     (WS_PH_OFF + WS_SPLIT_B)
#define WS_TOT_OFF    (WS_PL_OFF + WS_SPLIT_B)
#define WS_P29_OFF    (WS_TOT_OFF + (size_t)BN * BN * 4)

__device__ __forceinline__ u16 bf16_rne(float f) {
    u32 u = __float_as_uint(f);
    u32 r = u + 0x7fffu + ((u >> 16) & 1u);
    return (u16)(r >> 16);
}

// ---------------- E -> (hi, lo) bf16 split ----------------
__global__ __launch_bounds__(256) void conv_kernel(const float* __restrict__ x,
                                                   u16* __restrict__ hi,
                                                   u16* __restrict__ lo) {
    int i = blockIdx.x * 256 + threadIdx.x;     // float4 index
    float4 v = ((const float4*)x)[i];
    float vv[4] = {v.x, v.y, v.z, v.w};
    u16 h[4], l[4];
#pragma unroll
    for (int k = 0; k < 4; ++k) {
        h[k] = bf16_rne(vv[k]);
        float hf = __uint_as_float((u32)h[k] << 16);
        l[k] = bf16_rne(vv[k] - hf);
    }
    ((ushort4*)hi)[i] = make_ushort4(h[0], h[1], h[2], h[3]);
    ((ushort4*)lo)[i] = make_ushort4(l[0], l[1], l[2], l[3]);
}

// ---------------- pred (fp32) -> split bf16 (+ fp32 copy for t=29) ----------
__global__ __launch_bounds__(256) void pred_kernel(
    const float* __restrict__ rep, const float* __restrict__ Ww,
    const float* __restrict__ Wb, u16* __restrict__ Ph, u16* __restrict__ Pl,
    float* __restrict__ pred29)
{
    __shared__ float rep_s[64 * 132];
    __shared__ float w_s[64 * 132];
    const int t  = blockIdx.z;
    const int c0 = blockIdx.y * 64;
    const int d0 = blockIdx.x * 64;
    const int tid = threadIdx.x;
    const int tx = tid & 15, ty = tid >> 4;

    for (int it = 0; it < 8; ++it) {
        int idx = tid + it * 256;
        int row = idx >> 5;
        int off = (idx & 31) * 4;
        *(float4*)&rep_s[row * 132 + off] =
            *(const float4*)&rep[(size_t)(c0 + row) * DHH + off];
        *(float4*)&w_s[row * 132 + off] =
            *(const float4*)&Ww[((size_t)t * DD + d0 + row) * DHH + off];
    }
    __syncthreads();

    float acc[4][4] = {};
    for (int k = 0; k < DHH; k += 4) {
        float4 e[4], p[4];
#pragma unroll
        for (int i = 0; i < 4; ++i) e[i] = *(const float4*)&rep_s[(i * 16 + ty) * 132 + k];
#pragma unroll
        for (int j = 0; j < 4; ++j) p[j] = *(const float4*)&w_s[(j * 16 + tx) * 132 + k];
#pragma unroll
        for (int i = 0; i < 4; ++i)
#pragma unroll
            for (int j = 0; j < 4; ++j) {
                acc[i][j] = fmaf(e[i].x, p[j].x, acc[i][j]);
                acc[i][j] = fmaf(e[i].y, p[j].y, acc[i][j]);
                acc[i][j] = fmaf(e[i].z, p[j].z, acc[i][j]);
                acc[i][j] = fmaf(e[i].w, p[j].w, acc[i][j]);
            }
    }

#pragma unroll
    for (int j = 0; j < 4; ++j) {
        float bj = Wb[(size_t)t * DD + d0 + j * 16 + tx];
#pragma unroll
        for (int i = 0; i < 4; ++i) {
            float v = acc[i][j] + bj;
            size_t idx = ((size_t)t * BN + c0 + i * 16 + ty) * DD + d0 + j * 16 + tx;
            u16 h = bf16_rne(v);
            float hf = __uint_as_float((u32)h << 16);
            Ph[idx] = h;
            Pl[idx] = bf16_rne(v - hf);
            if (t == T_PRED - 1)
                pred29[(size_t)(c0 + i * 16 + ty) * DD + d0 + j * 16 + tx] = v;
        }
    }
}

// ---------------- fused totals MFMA + online softmax + diag ----------------
// block: 256 thr = 4 waves; tile 128 rows x 128 cols per col-iter; BK=32.
// wave w: rows (w>>1)*64, cols (w&1)*64 (64x64 = 4x4 mfma 16x16x32).
// staging: wave w stages tile w of {A_hi,A_lo,B_hi,B_lo} via global_load_lds,
// packed 64 B rows (bank-balanced for the quad-strided b128 frag reads).
__global__ __launch_bounds__(256) void nce_kernel(
    const u16* __restrict__ Eh, const u16* __restrict__ El,
    const u16* __restrict__ Ph, const u16* __restrict__ Pl,
    float* __restrict__ nce_acc)
{
    __shared__ u16 lds[4 * 128 * BK];    // 32 KB: A_hi | A_lo | B_hi | B_lo
    __shared__ float red_m[4][64];
    __shared__ float red_s[4][64];
    __shared__ float red_c[8];

    const int t    = blockIdx.y;
    const int row0 = blockIdx.x * 128;
    const int tid  = threadIdx.x;
    const int lane = tid & 63;
    const int w    = tid >> 6;
    const int ml   = lane & 15;
    const int quad = lane >> 4;
    const int wr   = (w >> 1) * 64;
    const int wc   = (w & 1) * 64;
    const int row_in = lane >> 2;     // 0..15 within a 16-row staging chunk
    const int kq     = lane & 3;      // 16B sub-chunk within a 64B row

    u16* lbase = lds + w * (128 * BK);
    const u16* Ahp = lds;
    const u16* Alp = lds + 4096;
    const u16* Bhp = lds + 8192;
    const u16* Blp = lds + 12288;

    const bool isB = (w >= 2);
    const u16* gbase;
    if (w == 0)      gbase = Eh + ((size_t)t * BN + row0) * DD;
    else if (w == 1) gbase = El + ((size_t)t * BN + row0) * DD;
    else if (w == 2) gbase = Ph + (size_t)t * BN * DD;
    else             gbase = Pl + (size_t)t * BN * DD;

    float mrun[4][4], srun[4][4];
#pragma unroll
    for (int i = 0; i < 4; ++i)
#pragma unroll
        for (int r = 0; r < 4; ++r) { mrun[i][r] = -3.0e38f; srun[i][r] = 0.f; }
    float dsum = 0.f;   // all diag hits for this lane (global sum is enough)

    for (int c0 = 0; c0 < BN; c0 += 128) {
        f32x4 acc[4][4];
#pragma unroll
        for (int i = 0; i < 4; ++i)
#pragma unroll
            for (int j = 0; j < 4; ++j) acc[i][j] = (f32x4){0.f, 0.f, 0.f, 0.f};

        const u16* gs = isB ? gbase + (size_t)c0 * DD : gbase;

        for (int k0 = 0; k0 < DD; k0 += BK) {
            __syncthreads();   // previous chunk's frag reads done
#pragma unroll
            for (int n = 0; n < 8; ++n) {
                const u16* g = gs + (size_t)(n * 16 + row_in) * DD + k0 + kq * 8;
                __builtin_amdgcn_global_load_lds(
                    (const __attribute__((address_space(1))) u32*)g,
                    (__attribute__((address_space(3))) u32*)(lbase + n * 512),
                    16, 0, 0);
            }
            __syncthreads();   // drains vmcnt: staging visible

            short8 ah[4], al[4], bh[4], bl[4];
#pragma unroll
            for (int i = 0; i < 4; ++i) {
                ah[i] = *(const short8*)&Ahp[(wr + i * 16 + ml) * BK + quad * 8];
                al[i] = *(const short8*)&Alp[(wr + i * 16 + ml) * BK + quad * 8];
            }
#pragma unroll
            for (int j = 0; j < 4; ++j) {
                bh[j] = *(const short8*)&Bhp[(wc + j * 16 + ml) * BK + quad * 8];
                bl[j] = *(const short8*)&Blp[(wc + j * 16 + ml) * BK + quad * 8];
            }
#pragma unroll
            for (int i = 0; i < 4; ++i)
#pragma unroll
                for (int j = 0; j < 4; ++j) {
                    acc[i][j] = __builtin_amdgcn_mfma_f32_16x16x32_bf16(ah[i], bh[j], acc[i][j], 0, 0, 0);
                    acc[i][j] = __builtin_amdgcn_mfma_f32_16x16x32_bf16(ah[i], bl[j], acc[i][j], 0, 0, 0);
                    acc[i][j] = __builtin_amdgcn_mfma_f32_16x16x32_bf16(al[i], bh[j], acc[i][j], 0, 0, 0);
                }
        }

        // lane-local online softmax over this col-iter's 4 cols per row-state
#pragma unroll
        for (int i = 0; i < 4; ++i) {
#pragma unroll
            for (int r = 0; r < 4; ++r) {
                float x0 = acc[i][0][r], x1 = acc[i][1][r];
                float x2 = acc[i][2][r], x3 = acc[i][3][r];
                float tmax = fmaxf(fmaxf(x0, x1), fmaxf(x2, x3));
                float mo = mrun[i][r];
                float mn = fmaxf(mo, tmax);
                float ps = __expf(x0 - mn) + __expf(x1 - mn) +
                           __expf(x2 - mn) + __expf(x3 - mn);
                srun[i][r] = srun[i][r] * __expf(mo - mn) + ps;
                mrun[i][r] = mn;
                if (quad * 4 + r == ml) {  // this lane may hold the diag element
                    int rr = row0 + wr + i * 16 + quad * 4 + r;
#pragma unroll
                    for (int j = 0; j < 4; ++j)
                        if (c0 + wc + j * 16 + ml == rr) dsum += acc[i][j][r];
                }
            }
        }
    }

    // merge (m,s) across the 16 lanes of each quad (cols of the wave slice)
#pragma unroll
    for (int i = 0; i < 4; ++i)
#pragma unroll
        for (int r = 0; r < 4; ++r) {
            float m = mrun[i][r], s = srun[i][r];
#pragma unroll
            for (int o = 1; o < 16; o <<= 1) {
                float mo2 = __shfl_xor(m, o, 64);
                float so2 = __shfl_xor(s, o, 64);
                float mn = fmaxf(m, mo2);
                s = s * __expf(m - mn) + so2 * __expf(mo2 - mn);
                m = mn;
            }
            mrun[i][r] = m; srun[i][r] = s;
        }
    if (ml == 0) {
#pragma unroll
        for (int i = 0; i < 4; ++i)
#pragma unroll
            for (int r = 0; r < 4; ++r) {
                int rl = i * 16 + quad * 4 + r;
                red_m[w][rl] = mrun[i][r];
                red_s[w][rl] = srun[i][r];
            }
    }
    float dv = dsum;
#pragma unroll
    for (int o = 1; o < 64; o <<= 1) dv += __shfl_xor(dv, o, 64);
    if (lane == 0) red_c[4 + w] = dv;
    __syncthreads();

    float contrib = 0.f;
    if (tid < 128) {
        int row = tid;
        int wA = (row >> 6) * 2, rl = row & 63;
        float mA = red_m[wA][rl],     sA = red_s[wA][rl];
        float mB = red_m[wA + 1][rl], sB = red_s[wA + 1][rl];
        float mn = fmaxf(mA, mB);
        float s = sA * __expf(mA - mn) + sB * __expf(mB - mn);
        contrib = mn + __logf(s);                 // lse for this row
#pragma unroll
        for (int o = 1; o < 64; o <<= 1) contrib += __shfl_xor(contrib, o, 64);
        if (lane == 0) red_c[w] = contrib;
    }
    __syncthreads();
    if (tid == 0) {
        float tot = red_c[0] + red_c[1]
                  - (red_c[4] + red_c[5] + red_c[6] + red_c[7]);
        atomicAdd(nce_acc, tot);
    }
}

// ---------------- exact fp32 totals for t=29 (argmax insurance) ------------
// block: 64 rows x 256 cols (4 col-tiles of 64); grid (32, 8).
__global__ __launch_bounds__(256) void t29_kernel(
    const float* __restrict__ E, const float* __restrict__ P29,
    float* __restrict__ tot29)
{
    __shared__ float e_s[64 * 260];
    __shared__ float p_s[64 * 260];
    const int row0 = blockIdx.x * 64;
    const int cb0  = blockIdx.y * 256;
    const int tid  = threadIdx.x;
    const int tx = tid & 15, ty = tid >> 4;

    for (int it = 0; it < 16; ++it) {
        int idx = tid + it * 256;
        int row = idx >> 6;
        int off = (idx & 63) * 4;
        *(float4*)&e_s[row * 260 + off] =
            *(const float4*)&E[((size_t)(T_PRED - 1) * BN + row0 + row) * DD + off];
    }

    for (int cc0 = cb0; cc0 < cb0 + 256; cc0 += 64) {
        __syncthreads();
        for (int it = 0; it < 16; ++it) {
            int idx = tid + it * 256;
            int row = idx >> 6;
            int off = (idx & 63) * 4;
            *(float4*)&p_s[row * 260 + off] =
                *(const float4*)&P29[(size_t)(cc0 + row) * DD + off];
        }
        __syncthreads();

        float acc[4][4] = {};
        for (int k = 0; k < DD; k += 4) {
            float4 e[4], p[4];
#pragma unroll
            for (int i = 0; i < 4; ++i) e[i] = *(const float4*)&e_s[(i * 16 + ty) * 260 + k];
#pragma unroll
            for (int j = 0; j < 4; ++j) p[j] = *(const float4*)&p_s[(j * 16 + tx) * 260 + k];
#pragma unroll
            for (int i = 0; i < 4; ++i)
#pragma unroll
                for (int j = 0; j < 4; ++j) {
                    acc[i][j] = fmaf(e[i].x, p[j].x, acc[i][j]);
                    acc[i][j] = fmaf(e[i].y, p[j].y, acc[i][j]);
                    acc[i][j] = fmaf(e[i].z, p[j].z, acc[i][j]);
                    acc[i][j] = fmaf(e[i].w, p[j].w, acc[i][j]);
                }
        }
#pragma unroll
        for (int i = 0; i < 4; ++i)
#pragma unroll
            for (int j = 0; j < 4; ++j)
                tot29[(size_t)(row0 + i * 16 + ty) * BN + cc0 + j * 16 + tx] = acc[i][j];
    }
}

// lse29 from materialized tot29: one wave per row, two passes (max, sum)
__global__ __launch_bounds__(256) void lse_kernel(const float* __restrict__ tot29,
                                                  float* __restrict__ lse29)
{
    const int lane = threadIdx.x & 63;
    const int row  = blockIdx.x * 4 + (threadIdx.x >> 6);
    const float* rp = tot29 + (size_t)row * BN;
    float mx = -3.4e38f;
    for (int c = lane * 4; c < BN; c += 256) {
        float4 v = *(const float4*)&rp[c];
        mx = fmaxf(mx, fmaxf(fmaxf(v.x, v.y), fmaxf(v.z, v.w)));
    }
#pragma unroll
    for (int o = 1; o < 64; o <<= 1) mx = fmaxf(mx, __shfl_xor(mx, o, 64));
    float s = 0.f;
    for (int c = lane * 4; c < BN; c += 256) {
        float4 v = *(const float4*)&rp[c];
        s += __expf(v.x - mx) + __expf(v.y - mx) + __expf(v.z - mx) + __expf(v.w - mx);
    }
#pragma unroll
    for (int o = 1; o < 64; o <<= 1) s += __shfl_xor(s, o, 64);
    if (lane == 0) lse29[row] = mx + __logf(s);
}

// argmax over b of (tot29[b,c] - lse29[b]) via packed atomicMax
__device__ __forceinline__ u32 fenc(float f) {
    u32 u = __float_as_uint(f);
    return (u & 0x80000000u) ? ~u : (u | 0x80000000u);
}

__global__ __launch_bounds__(256) void argmax_kernel(
    const float* __restrict__ tot29, const float* __restrict__ lse29,
    u64* __restrict__ table)
{
    int c  = blockIdx.x * 256 + threadIdx.x;
    int b0 = blockIdx.y * 128;
    float best = -3.4e38f; int bi = 0;
    for (int b = b0; b < b0 + 128; ++b) {
        float v = tot29[(size_t)b * BN + c] - lse29[b];
        if (v > best) { best = v; bi = b; }
    }
    u64 key = ((u64)fenc(best) << 32) | (u32)(0xFFFFFFFFu - (u32)bi);
    atomicMax(table + c, key);
}

__global__ __launch_bounds__(256) void count_kernel(const u64* __restrict__ table,
                                                    int* __restrict__ correct)
{
    int c = blockIdx.x * 256 + threadIdx.x;
    u32 bi = 0xFFFFFFFFu - (u32)(table[c] & 0xFFFFFFFFull);
    if ((int)bi == c) atomicAdd(correct, 1);
}

__global__ void fin_kernel(const float* __restrict__ nce_acc,
                           const int* __restrict__ correct,
                           float* __restrict__ out)
{
    if (threadIdx.x == 0) {
        out[0] = (float)(*correct) / (float)BN;
        out[1] = (*nce_acc) / (float)(BN * T_PRED);
        out[2] = (float)BN;
        out[3] = (float)(BN * T_PRED);
    }
}

extern "C" void kernel_launch(void* const* d_in, const int* in_sizes, int n_in,
                              void* d_out, int out_size, void* d_ws, size_t ws_size,
                              hipStream_t stream) {
    const float* E   = (const float*)d_in[0];   // [T,B,D]
    const float* rep = (const float*)d_in[1];   // [B,DH]
    const float* Ww  = (const float*)d_in[2];   // [T,D,DH]
    const float* Wb  = (const float*)d_in[3];   // [T,D]
    float* out = (float*)d_out;

    char* ws = (char*)d_ws;
    float* nce_acc = (float*)(ws + 0);
    int*   correct = (int*)(ws + 8);
    u64*   table   = (u64*)(ws + WS_ARG_OFF);
    float* lse29   = (float*)(ws + WS_LSE_OFF);
    u16*   Eh      = (u16*)(ws + WS_EH_OFF);
    u16*   El      = (u16*)(ws + WS_EL_OFF);
    u16*   Ph      = (u16*)(ws + WS_PH_OFF);
    u16*   Pl      = (u16*)(ws + WS_PL_OFF);
    float* tot29   = (float*)(ws + WS_TOT_OFF);
    float* pred29  = (float*)(ws + WS_P29_OFF);

    hipMemsetAsync(ws, 0, 20480, stream);  // nce_acc, correct, argmax table
    conv_kernel<<<dim3((T_PRED * BN * DD) / 4 / 256), 256, 0, stream>>>(E, Eh, El);
    pred_kernel<<<dim3(4, 32, 30), 256, 0, stream>>>(rep, Ww, Wb, Ph, Pl, pred29);
    nce_kernel<<<dim3(16, 30), 256, 0, stream>>>(Eh, El, Ph, Pl, nce_acc);
    t29_kernel<<<dim3(32, 8), 256, 0, stream>>>(E, pred29, tot29);
    lse_kernel<<<dim3(512), 256, 0, stream>>>(tot29, lse29);
    argmax_kernel<<<dim3(8, 16), 256, 0, stream>>>(tot29, lse29, table);
    count_kernel<<<dim3(8), 256, 0, stream>>>(table, correct);
    fin_kernel<<<1, 64, 0, stream>>>(nce_acc, correct, out);
}

// Round 3
// 279.178 us; speedup vs baseline: 5.8142x; 1.7975x over previous
//
#include <hip/hip_runtime.h>
#include <math.h>

typedef unsigned short u16;
typedef unsigned int   u32;
typedef unsigned long long u64;

#define T_PRED 30
#define BN 2048
#define DD 256
#define DHH 128

typedef __attribute__((ext_vector_type(8))) short short8;   // 8 x bf16
typedef __attribute__((ext_vector_type(4))) float f32x4;

// ---- workspace layout (~116 MB) ----
#define WS_ARG_OFF    4096                                   // u64 table[2048]
#define WS_LSE_OFF    20480                                  // f32 lse29[2048]
#define WS_RH_OFF     32768                                  // rep hi  [2048*128] u16
#define WS_RL_OFF     (WS_RH_OFF + 524288)
#define WS_WH_OFF     (WS_RL_OFF + 524288)                   // W^T hi [30*128*256] u16
#define WS_WL_OFF     (WS_WH_OFF + 1966080)
#define WS_EH_OFF     (WS_WL_OFF + 1966080)                  // E hi [30*2048*256] u16
#define WS_EL_OFF     (WS_EH_OFF + 31457280)
#define WS_GH_OFF     (WS_EL_OFF + 31457280)                 // G hi [30*2048*128] u16
#define WS_GL_OFF     (WS_GH_OFF + 15728640)
#define WS_TOT_OFF    (WS_GL_OFF + 15728640)                 // tot29 f32 [2048*2048]

__device__ __forceinline__ u16 bf16_rne(float f) {
    u32 u = __float_as_uint(f);
    u32 r = u + 0x7fffu + ((u >> 16) & 1u);
    return (u16)(r >> 16);
}

// ---------------- generic fp32 -> (hi, lo) bf16 split, float4 per thread ----
__global__ __launch_bounds__(256) void conv_kernel(const float* __restrict__ x,
                                                   u16* __restrict__ hi,
                                                   u16* __restrict__ lo) {
    int i = blockIdx.x * 256 + threadIdx.x;
    float4 v = ((const float4*)x)[i];
    float vv[4] = {v.x, v.y, v.z, v.w};
    u16 h[4], l[4];
#pragma unroll
    for (int k = 0; k < 4; ++k) {
        h[k] = bf16_rne(vv[k]);
        float hf = __uint_as_float((u32)h[k] << 16);
        l[k] = bf16_rne(vv[k] - hf);
    }
    ((ushort4*)hi)[i] = make_ushort4(h[0], h[1], h[2], h[3]);
    ((ushort4*)lo)[i] = make_ushort4(l[0], l[1], l[2], l[3]);
}

// ---------------- W[t,d,h] -> W^T splits [t,h,d] -------------------------
__global__ __launch_bounds__(256) void conv_w_kernel(const float* __restrict__ Ww,
                                                     u16* __restrict__ Wh,
                                                     u16* __restrict__ Wl) {
    __shared__ float tile[64][132];
    const int t  = blockIdx.y;
    const int d0 = blockIdx.x * 64;
    const int tid = threadIdx.x;
    for (int it = 0; it < 8; ++it) {
        int idx = tid + it * 256;
        int row = idx >> 5;             // 32 float4 per 128-float row
        int off = (idx & 31) * 4;
        *(float4*)&tile[row][off] =
            *(const float4*)&Ww[((size_t)t * DD + d0 + row) * DHH + off];
    }
    __syncthreads();
    const int h = tid & 127, part = tid >> 7;     // two 32-d halves
    for (int dd = 0; dd < 32; ++dd) {
        int d = part * 32 + dd;
        float v = tile[d][h];
        u16 hb = bf16_rne(v);
        float hf = __uint_as_float((u32)hb << 16);
        size_t o = (size_t)t * DHH * DD + (size_t)h * DD + d0 + d;
        Wh[o] = hb;
        Wl[o] = bf16_rne(v - hf);
    }
}

// ---------------- G[t] = E[t] @ W[t]  (split-bf16 MFMA, out = split) -------
// tile 128(b) x 128(h), K=256 in 8 chunks of 32. 4 waves; wave w stages tile w
// (Eh/El/Wh/Wl chunk 128x32). Swizzled slots: slot = (chunk + (row>>1)) & 3.
__global__ __launch_bounds__(256) void g_kernel(
    const u16* __restrict__ Eh, const u16* __restrict__ El,
    const u16* __restrict__ Wh, const u16* __restrict__ Wl,
    u16* __restrict__ Gh, u16* __restrict__ Gl)
{
    __shared__ u16 sm[4][4096];        // 8 KB each: Eh | El | Wh | Wl chunk
    const int t    = blockIdx.y;
    const int row0 = blockIdx.x * 128;
    const int tid  = threadIdx.x;
    const int lane = tid & 63;
    const int w    = tid >> 6;
    const int ml   = lane & 15;
    const int quad = lane >> 4;
    const int wr   = (w >> 1) * 64;
    const int wc   = (w & 1) * 64;

    const u16* gb;
    if (w == 0)      gb = Eh + ((size_t)t * BN + row0) * DD;
    else if (w == 1) gb = El + ((size_t)t * BN + row0) * DD;
    else if (w == 2) gb = Wh + (size_t)t * DHH * DD;
    else             gb = Wl + (size_t)t * DHH * DD;

    const int srow  = lane >> 2;        // 0..15 within 16-row staging chunk
    const int sslot = lane & 3;

    f32x4 acc[4][4];
#pragma unroll
    for (int i = 0; i < 4; ++i)
#pragma unroll
        for (int j = 0; j < 4; ++j) acc[i][j] = (f32x4){0.f, 0.f, 0.f, 0.f};

    for (int kc = 0; kc < 8; ++kc) {
        __syncthreads();
#pragma unroll
        for (int n = 0; n < 8; ++n) {
            int row = n * 16 + srow;
            int c = (sslot - (row >> 1)) & 3;
            const u16* g = gb + (size_t)row * DD + kc * 32 + c * 8;
            __builtin_amdgcn_global_load_lds(
                (const __attribute__((address_space(1))) u32*)g,
                (__attribute__((address_space(3))) u32*)(&sm[w][n * 512]),
                16, 0, 0);
        }
        __syncthreads();

        short8 ah[4], al[4], bh[4], bl[4];
#pragma unroll
        for (int i = 0; i < 4; ++i) {
            int r = wr + i * 16 + ml;
            int su = ((quad + (r >> 1)) & 3) * 8;
            ah[i] = *(const short8*)&sm[0][r * 32 + su];
            al[i] = *(const short8*)&sm[1][r * 32 + su];
        }
#pragma unroll
        for (int j = 0; j < 4; ++j) {
            int r = wc + j * 16 + ml;
            int su = ((quad + (r >> 1)) & 3) * 8;
            bh[j] = *(const short8*)&sm[2][r * 32 + su];
            bl[j] = *(const short8*)&sm[3][r * 32 + su];
        }
#pragma unroll
        for (int i = 0; i < 4; ++i)
#pragma unroll
            for (int j = 0; j < 4; ++j) {
                acc[i][j] = __builtin_amdgcn_mfma_f32_16x16x32_bf16(ah[i], bh[j], acc[i][j], 0, 0, 0);
                acc[i][j] = __builtin_amdgcn_mfma_f32_16x16x32_bf16(ah[i], bl[j], acc[i][j], 0, 0, 0);
                acc[i][j] = __builtin_amdgcn_mfma_f32_16x16x32_bf16(al[i], bh[j], acc[i][j], 0, 0, 0);
            }
    }

#pragma unroll
    for (int i = 0; i < 4; ++i)
#pragma unroll
        for (int j = 0; j < 4; ++j)
#pragma unroll
            for (int r = 0; r < 4; ++r) {
                int row = row0 + wr + i * 16 + quad * 4 + r;
                int h   = wc + j * 16 + ml;
                float v = acc[i][j][r];
                u16 hb = bf16_rne(v);
                float hf = __uint_as_float((u32)hb << 16);
                size_t o = ((size_t)t * BN + row) * DHH + h;
                Gh[o] = hb;
                Gl[o] = bf16_rne(v - hf);
            }
}

// ---------------- fused totals MFMA + online softmax + diag ----------------
// totals'[t] = G[t] @ rep^T (bias dropped: cancels in softmax/diag/argmax).
// Block: 64 rows x full 2048 cols (16 col-tiles of 128). 4 waves, wave tile
// 32x64. A-frags (G, K=128) register-resident; LDS stages rep tile per c0.
// 256B LDS rows, 16 slots, swizzle slot = (chunk + row) & 15.
__global__ __launch_bounds__(256, 2) void nce_kernel(
    const u16* __restrict__ Gh, const u16* __restrict__ Gl,
    const u16* __restrict__ Rh, const u16* __restrict__ Rl,
    float* __restrict__ nce_acc, float* __restrict__ tot29,
    float* __restrict__ lse29)
{
    __shared__ u16 bsm[2][16384];       // 32 KB each: rep hi | rep lo tile
    __shared__ float red_m[4][32];
    __shared__ float red_s[4][32];
    __shared__ float red_c[8];

    const int t    = blockIdx.y;
    const int row0 = blockIdx.x * 64;
    const int tid  = threadIdx.x;
    const int lane = tid & 63;
    const int w    = tid >> 6;
    const int ml   = lane & 15;
    const int quad = lane >> 4;
    const int wr   = (w >> 1) * 32;
    const int wc   = (w & 1) * 64;
    const bool last = (t == T_PRED - 1);

    // ---- preload A-frags (G rows, full K=128) into registers ----
    short8 ah[2][4], al[2][4];
#pragma unroll
    for (int i = 0; i < 2; ++i)
#pragma unroll
        for (int kc = 0; kc < 4; ++kc) {
            size_t o = ((size_t)t * BN + row0 + wr + i * 16 + ml) * DHH + kc * 32 + quad * 8;
            ah[i][kc] = *(const short8*)(Gh + o);
            al[i][kc] = *(const short8*)(Gl + o);
        }

    float mrun[2][4], srun[2][4];
#pragma unroll
    for (int i = 0; i < 2; ++i)
#pragma unroll
        for (int r = 0; r < 4; ++r) { mrun[i][r] = -3.0e38f; srun[i][r] = 0.f; }
    float dsum = 0.f;

    const int srow  = lane >> 4;        // 0..3: row within 4-row staging instr
    const int sslot = lane & 15;

    for (int c0 = 0; c0 < BN; c0 += 128) {
        __syncthreads();
        // stage rep tile [c0..c0+128) x 128k, hi+lo: 64 x 1KB instrs
#pragma unroll
        for (int n = 0; n < 16; ++n) {
            int q = w * 16 + n;
            int split = q >> 5;
            int row4 = (q & 31) * 4;
            int row = row4 + srow;
            int c = (sslot - row) & 15;
            const u16* g = (split ? Rl : Rh) + (size_t)(c0 + row) * DHH + c * 8;
            __builtin_amdgcn_global_load_lds(
                (const __attribute__((address_space(1))) u32*)g,
                (__attribute__((address_space(3))) u32*)(&bsm[split][row4 * 128]),
                16, 0, 0);
        }
        __syncthreads();

        f32x4 acc[2][4];
#pragma unroll
        for (int i = 0; i < 2; ++i)
#pragma unroll
            for (int j = 0; j < 4; ++j) acc[i][j] = (f32x4){0.f, 0.f, 0.f, 0.f};

#pragma unroll
        for (int kc = 0; kc < 4; ++kc) {
            short8 bh[4], bl[4];
#pragma unroll
            for (int j = 0; j < 4; ++j) {
                int r = wc + j * 16 + ml;
                int su = ((kc * 4 + quad + r) & 15) * 8;
                bh[j] = *(const short8*)&bsm[0][r * 128 + su];
                bl[j] = *(const short8*)&bsm[1][r * 128 + su];
            }
#pragma unroll
            for (int i = 0; i < 2; ++i)
#pragma unroll
                for (int j = 0; j < 4; ++j) {
                    acc[i][j] = __builtin_amdgcn_mfma_f32_16x16x32_bf16(ah[i][kc], bh[j], acc[i][j], 0, 0, 0);
                    acc[i][j] = __builtin_amdgcn_mfma_f32_16x16x32_bf16(ah[i][kc], bl[j], acc[i][j], 0, 0, 0);
                    acc[i][j] = __builtin_amdgcn_mfma_f32_16x16x32_bf16(al[i][kc], bh[j], acc[i][j], 0, 0, 0);
                }
        }

        // online softmax + diag + t29 spill
#pragma unroll
        for (int i = 0; i < 2; ++i) {
#pragma unroll
            for (int r = 0; r < 4; ++r) {
                float x0 = acc[i][0][r], x1 = acc[i][1][r];
                float x2 = acc[i][2][r], x3 = acc[i][3][r];
                float tmax = fmaxf(fmaxf(x0, x1), fmaxf(x2, x3));
                float mo = mrun[i][r];
                float mn = fmaxf(mo, tmax);
                float ps = __expf(x0 - mn) + __expf(x1 - mn) +
                           __expf(x2 - mn) + __expf(x3 - mn);
                srun[i][r] = srun[i][r] * __expf(mo - mn) + ps;
                mrun[i][r] = mn;
                int rr = row0 + wr + i * 16 + quad * 4 + r;
#pragma unroll
                for (int j = 0; j < 4; ++j) {
                    int cc = c0 + wc + j * 16 + ml;
                    if (cc == rr) dsum += acc[i][j][r];
                    if (last) tot29[(size_t)rr * BN + cc] = acc[i][j][r];
                }
            }
        }
    }

    // merge (m,s) across the 16 ml-lanes sharing each row
#pragma unroll
    for (int i = 0; i < 2; ++i)
#pragma unroll
        for (int r = 0; r < 4; ++r) {
            float m = mrun[i][r], s = srun[i][r];
#pragma unroll
            for (int o = 1; o < 16; o <<= 1) {
                float mo2 = __shfl_xor(m, o, 64);
                float so2 = __shfl_xor(s, o, 64);
                float mn = fmaxf(m, mo2);
                s = s * __expf(m - mn) + so2 * __expf(mo2 - mn);
                m = mn;
            }
            mrun[i][r] = m; srun[i][r] = s;
        }
    if (ml == 0) {
#pragma unroll
        for (int i = 0; i < 2; ++i)
#pragma unroll
            for (int r = 0; r < 4; ++r) {
                int rl = i * 16 + quad * 4 + r;   // 0..31 within wave rows
                red_m[w][rl] = mrun[i][r];
                red_s[w][rl] = srun[i][r];
            }
    }
    float dv = dsum;
#pragma unroll
    for (int o = 1; o < 64; o <<= 1) dv += __shfl_xor(dv, o, 64);
    if (lane == 0) red_c[4 + w] = dv;
    __syncthreads();

    if (tid < 64) {
        int row = tid;                       // 0..63 local
        int wA = (row >> 5) * 2, rl = row & 31;
        float mA = red_m[wA][rl],     sA = red_s[wA][rl];
        float mB = red_m[wA + 1][rl], sB = red_s[wA + 1][rl];
        float mn = fmaxf(mA, mB);
        float s = sA * __expf(mA - mn) + sB * __expf(mB - mn);
        float lse = mn + __logf(s);
        if (last) lse29[row0 + row] = lse;
        float contrib = lse;
#pragma unroll
        for (int o = 1; o < 64; o <<= 1) contrib += __shfl_xor(contrib, o, 64);
        if (lane == 0) red_c[0] = contrib;
    }
    __syncthreads();
    if (tid == 0) {
        float tot = red_c[0] - (red_c[4] + red_c[5] + red_c[6] + red_c[7]);
        atomicAdd(nce_acc, tot);
    }
}

// argmax over b of (tot29[b,c] - lse29[b]) via packed atomicMax
__device__ __forceinline__ u32 fenc(float f) {
    u32 u = __float_as_uint(f);
    return (u & 0x80000000u) ? ~u : (u | 0x80000000u);
}

__global__ __launch_bounds__(256) void argmax_kernel(
    const float* __restrict__ tot29, const float* __restrict__ lse29,
    u64* __restrict__ table)
{
    int c  = blockIdx.x * 256 + threadIdx.x;
    int b0 = blockIdx.y * 128;
    float best = -3.4e38f; int bi = 0;
    for (int b = b0; b < b0 + 128; ++b) {
        float v = tot29[(size_t)b * BN + c] - lse29[b];
        if (v > best) { best = v; bi = b; }
    }
    u64 key = ((u64)fenc(best) << 32) | (u32)(0xFFFFFFFFu - (u32)bi);
    atomicMax(table + c, key);
}

__global__ __launch_bounds__(256) void count_kernel(const u64* __restrict__ table,
                                                    int* __restrict__ correct)
{
    int c = blockIdx.x * 256 + threadIdx.x;
    u32 bi = 0xFFFFFFFFu - (u32)(table[c] & 0xFFFFFFFFull);
    if ((int)bi == c) atomicAdd(correct, 1);
}

__global__ void fin_kernel(const float* __restrict__ nce_acc,
                           const int* __restrict__ correct,
                           float* __restrict__ out)
{
    if (threadIdx.x == 0) {
        out[0] = (float)(*correct) / (float)BN;
        out[1] = (*nce_acc) / (float)(BN * T_PRED);
        out[2] = (float)BN;
        out[3] = (float)(BN * T_PRED);
    }
}

extern "C" void kernel_launch(void* const* d_in, const int* in_sizes, int n_in,
                              void* d_out, int out_size, void* d_ws, size_t ws_size,
                              hipStream_t stream) {
    const float* E   = (const float*)d_in[0];   // [T,B,D]
    const float* rep = (const float*)d_in[1];   // [B,DH]
    const float* Ww  = (const float*)d_in[2];   // [T,D,DH]
    float* out = (float*)d_out;

    char* ws = (char*)d_ws;
    float* nce_acc = (float*)(ws + 0);
    int*   correct = (int*)(ws + 8);
    u64*   table   = (u64*)(ws + WS_ARG_OFF);
    float* lse29   = (float*)(ws + WS_LSE_OFF);
    u16*   Rh      = (u16*)(ws + WS_RH_OFF);
    u16*   Rl      = (u16*)(ws + WS_RL_OFF);
    u16*   Wh      = (u16*)(ws + WS_WH_OFF);
    u16*   Wl      = (u16*)(ws + WS_WL_OFF);
    u16*   Eh      = (u16*)(ws + WS_EH_OFF);
    u16*   El      = (u16*)(ws + WS_EL_OFF);
    u16*   Gh      = (u16*)(ws + WS_GH_OFF);
    u16*   Gl      = (u16*)(ws + WS_GL_OFF);
    float* tot29   = (float*)(ws + WS_TOT_OFF);

    hipMemsetAsync(ws, 0, 20480, stream);   // nce_acc, correct, argmax table
    conv_kernel<<<dim3((T_PRED * BN * DD) / 4 / 256), 256, 0, stream>>>(E, Eh, El);
    conv_kernel<<<dim3((BN * DHH) / 4 / 256), 256, 0, stream>>>(rep, Rh, Rl);
    conv_w_kernel<<<dim3(4, 30), 256, 0, stream>>>(Ww, Wh, Wl);
    g_kernel<<<dim3(16, 30), 256, 0, stream>>>(Eh, El, Wh, Wl, Gh, Gl);
    nce_kernel<<<dim3(32, 30), 256, 0, stream>>>(Gh, Gl, Rh, Rl, nce_acc, tot29, lse29);
    argmax_kernel<<<dim3(8, 16), 256, 0, stream>>>(tot29, lse29, table);
    count_kernel<<<dim3(8), 256, 0, stream>>>(table, correct);
    fin_kernel<<<1, 64, 0, stream>>>(nce_acc, correct, out);
}

// Round 4
// 270.983 us; speedup vs baseline: 5.9900x; 1.0302x over previous
//
#include <hip/hip_runtime.h>
#include <math.h>

typedef unsigned short u16;
typedef unsigned int   u32;
typedef unsigned long long u64;

#define T_PRED 30
#define BN 2048
#define DD 256
#define DHH 128

typedef __attribute__((ext_vector_type(8))) short short8;   // 8 x bf16
typedef __attribute__((ext_vector_type(4))) float f32x4;

// ---- workspace layout (~37 MB) ----
// 0: f32 nce_acc | 8: u32 done
#define WS_TABLE  4096                         // u64 table[2048] (16 KB)
#define WS_LSE    20480                        // f32 lse29[2048]
#define WS_WH     32768                        // u16 W^T hi [30][128][256]
#define WS_WL     (WS_WH + 1966080)
#define WS_RH     (WS_WL + 1966080)            // u16 rep hi [2048][128]
#define WS_RL     (WS_RH + 524288)
#define WS_GH     (WS_RL + 524288)             // u16 G hi [30][2048][128]
#define WS_GL29   (WS_GH + 15728640)           // u16 G lo (t=29 only) [2048][128]
#define WS_T29    (WS_GL29 + 524288)           // f32 tot29 [2048][2048]

__device__ __forceinline__ u16 bf16_rne(float f) {
    u32 u = __float_as_uint(f);
    u32 r = u + 0x7fffu + ((u >> 16) & 1u);
    return (u16)(r >> 16);
}

__device__ __forceinline__ short8 pack_hi8(const float* f) {   // truncation split
    short8 r;
#pragma unroll
    for (int k = 0; k < 8; ++k) r[k] = (short)(u16)(__float_as_uint(f[k]) >> 16);
    return r;
}
__device__ __forceinline__ short8 pack_lo8(const float* f) {
    short8 r;
#pragma unroll
    for (int k = 0; k < 8; ++k) {
        float hf = __uint_as_float(__float_as_uint(f[k]) & 0xffff0000u);
        r[k] = (short)bf16_rne(f[k] - hf);
    }
    return r;
}

// ---------------- prep: W transpose+split, rep split ----------------------
__global__ __launch_bounds__(256) void prep_kernel(
    const float* __restrict__ rep, const float* __restrict__ Ww,
    u16* __restrict__ Rh, u16* __restrict__ Rl,
    u16* __restrict__ Wh, u16* __restrict__ Wl)
{
    const int bx = blockIdx.x, tid = threadIdx.x;
    if (bx < 120) {
        __shared__ float tile[64][132];
        const int t = bx >> 2, d0 = (bx & 3) * 64;
        for (int it = 0; it < 8; ++it) {
            int idx = tid + it * 256;
            int row = idx >> 5, off = (idx & 31) * 4;
            *(float4*)&tile[row][off] =
                *(const float4*)&Ww[((size_t)t * DD + d0 + row) * DHH + off];
        }
        __syncthreads();
        const int h = tid & 127, part = tid >> 7;
        for (int dd = 0; dd < 32; ++dd) {
            int d = part * 32 + dd;
            float v = tile[d][h];
            u16 hb = bf16_rne(v);
            float hf = __uint_as_float((u32)hb << 16);
            size_t o = (size_t)t * DHH * DD + (size_t)h * DD + d0 + d;
            Wh[o] = hb;
            Wl[o] = bf16_rne(v - hf);
        }
    } else {
        int base = (bx - 120) * 256 + tid;            // float4 index, 8 blocks
        for (int p = 0; p < 32; ++p) {
            int i = base + p * 2048;
            float4 v = ((const float4*)rep)[i];
            float vv[4] = {v.x, v.y, v.z, v.w};
            u16 h[4], l[4];
#pragma unroll
            for (int k = 0; k < 4; ++k) {
                h[k] = bf16_rne(vv[k]);
                float hf = __uint_as_float((u32)h[k] << 16);
                l[k] = bf16_rne(vv[k] - hf);
            }
            ((ushort4*)Rh)[i] = make_ushort4(h[0], h[1], h[2], h[3]);
            ((ushort4*)Rl)[i] = make_ushort4(l[0], l[1], l[2], l[3]);
        }
    }
}

// ---------------- G[t] = E[t] @ W[t]^T : LDS-free, in-register E split -----
// 1-pass for t<29 (feeds nce only), 3-pass split for t=29 (feeds argmax).
__global__ __launch_bounds__(256) void g_kernel(
    const float* __restrict__ E, const u16* __restrict__ Wh,
    const u16* __restrict__ Wl, u16* __restrict__ Gh, u16* __restrict__ Gl29)
{
    const int t    = blockIdx.y;
    const int row0 = blockIdx.x * 128;
    const int tid  = threadIdx.x;
    const int lane = tid & 63;
    const int w    = tid >> 6;
    const int ml   = lane & 15;
    const int quad = lane >> 4;
    const int wr   = (w >> 1) * 64;
    const int wc   = (w & 1) * 64;
    const bool p3  = (t == T_PRED - 1);

    f32x4 acc[4][4];
#pragma unroll
    for (int i = 0; i < 4; ++i)
#pragma unroll
        for (int j = 0; j < 4; ++j) acc[i][j] = (f32x4){0.f, 0.f, 0.f, 0.f};

#pragma unroll 1
    for (int kc = 0; kc < 8; ++kc) {
        short8 ah[4], al[4], bh[4], bl[4];
#pragma unroll
        for (int i = 0; i < 4; ++i) {
            const float* ep = E + ((size_t)t * BN + row0 + wr + i * 16 + ml) * DD
                                + kc * 32 + quad * 8;
            float4 e0 = *(const float4*)ep;
            float4 e1 = *(const float4*)(ep + 4);
            float f[8] = {e0.x, e0.y, e0.z, e0.w, e1.x, e1.y, e1.z, e1.w};
            ah[i] = pack_hi8(f);
            if (p3) al[i] = pack_lo8(f);
        }
#pragma unroll
        for (int j = 0; j < 4; ++j) {
            size_t o = (size_t)t * DHH * DD + (size_t)(wc + j * 16 + ml) * DD
                     + kc * 32 + quad * 8;
            bh[j] = *(const short8*)(Wh + o);
            if (p3) bl[j] = *(const short8*)(Wl + o);
        }
#pragma unroll
        for (int i = 0; i < 4; ++i)
#pragma unroll
            for (int j = 0; j < 4; ++j) {
                acc[i][j] = __builtin_amdgcn_mfma_f32_16x16x32_bf16(ah[i], bh[j], acc[i][j], 0, 0, 0);
                if (p3) {
                    acc[i][j] = __builtin_amdgcn_mfma_f32_16x16x32_bf16(ah[i], bl[j], acc[i][j], 0, 0, 0);
                    acc[i][j] = __builtin_amdgcn_mfma_f32_16x16x32_bf16(al[i], bh[j], acc[i][j], 0, 0, 0);
                }
            }
    }

#pragma unroll
    for (int i = 0; i < 4; ++i)
#pragma unroll
        for (int j = 0; j < 4; ++j)
#pragma unroll
            for (int r = 0; r < 4; ++r) {
                int row = row0 + wr + i * 16 + quad * 4 + r;
                int col = wc + j * 16 + ml;
                float v = acc[i][j][r];
                u16 hb = bf16_rne(v);
                Gh[((size_t)t * BN + row) * DHH + col] = hb;
                if (p3) {
                    float hf = __uint_as_float((u32)hb << 16);
                    Gl29[(size_t)row * DHH + col] = bf16_rne(v - hf);
                }
            }
}

// ---------------- nce for t=0..28: LDS-free 1-pass MFMA + online softmax ---
// Block: 128 rows x 2048 cols (16 col-tiles of 128). A-frags register-resident.
__global__ __launch_bounds__(256) void nceA_kernel(
    const u16* __restrict__ Gh, const u16* __restrict__ Rh,
    float* __restrict__ nce_acc)
{
    __shared__ float red_m[4][64];
    __shared__ float red_s[4][64];
    __shared__ float red_c[8];

    const int t    = blockIdx.y;
    const int row0 = blockIdx.x * 128;
    const int tid  = threadIdx.x;
    const int lane = tid & 63;
    const int w    = tid >> 6;
    const int ml   = lane & 15;
    const int quad = lane >> 4;
    const int wr   = (w >> 1) * 64;
    const int wc   = (w & 1) * 64;

    short8 ah[4][4];
#pragma unroll
    for (int i = 0; i < 4; ++i)
#pragma unroll
        for (int kc = 0; kc < 4; ++kc)
            ah[i][kc] = *(const short8*)(Gh +
                ((size_t)t * BN + row0 + wr + i * 16 + ml) * DHH + kc * 32 + quad * 8);

    float m[4][4], s[4][4];
#pragma unroll
    for (int i = 0; i < 4; ++i)
#pragma unroll
        for (int r = 0; r < 4; ++r) { m[i][r] = -3.0e38f; s[i][r] = 0.f; }
    float dsum = 0.f;

#pragma unroll 1
    for (int c0 = 0; c0 < BN; c0 += 128) {
        f32x4 acc[4][4];
#pragma unroll
        for (int i = 0; i < 4; ++i)
#pragma unroll
            for (int j = 0; j < 4; ++j) acc[i][j] = (f32x4){0.f, 0.f, 0.f, 0.f};

#pragma unroll
        for (int kc = 0; kc < 4; ++kc) {
            short8 bh[4];
#pragma unroll
            for (int j = 0; j < 4; ++j)
                bh[j] = *(const short8*)(Rh +
                    (size_t)(c0 + wc + j * 16 + ml) * DHH + kc * 32 + quad * 8);
#pragma unroll
            for (int i = 0; i < 4; ++i)
#pragma unroll
                for (int j = 0; j < 4; ++j)
                    acc[i][j] = __builtin_amdgcn_mfma_f32_16x16x32_bf16(ah[i][kc], bh[j], acc[i][j], 0, 0, 0);
        }

        if (c0 == row0) {   // the only col-tile containing diagonal elements
#pragma unroll
            for (int i = 0; i < 4; ++i)
#pragma unroll
                for (int j = 0; j < 4; ++j)
#pragma unroll
                    for (int r = 0; r < 4; ++r)
                        if (wc + j * 16 + ml == wr + i * 16 + quad * 4 + r)
                            dsum += acc[i][j][r];
        }

#pragma unroll
        for (int i = 0; i < 4; ++i)
#pragma unroll
            for (int r = 0; r < 4; ++r) {
                float x0 = acc[i][0][r], x1 = acc[i][1][r];
                float x2 = acc[i][2][r], x3 = acc[i][3][r];
                float tmax = fmaxf(fmaxf(x0, x1), fmaxf(x2, x3));
                float mo = m[i][r];
                float mn = fmaxf(mo, tmax);
                float ps = __expf(x0 - mn) + __expf(x1 - mn) +
                           __expf(x2 - mn) + __expf(x3 - mn);
                s[i][r] = s[i][r] * __expf(mo - mn) + ps;
                m[i][r] = mn;
            }
    }

    // merge (m,s) across the 16 ml-lanes sharing each row
#pragma unroll
    for (int i = 0; i < 4; ++i)
#pragma unroll
        for (int r = 0; r < 4; ++r) {
            float mm = m[i][r], ss = s[i][r];
#pragma unroll
            for (int o = 1; o < 16; o <<= 1) {
                float mo2 = __shfl_xor(mm, o, 64);
                float so2 = __shfl_xor(ss, o, 64);
                float mn = fmaxf(mm, mo2);
                ss = ss * __expf(mm - mn) + so2 * __expf(mo2 - mn);
                mm = mn;
            }
            m[i][r] = mm; s[i][r] = ss;
        }
    if (ml == 0) {
#pragma unroll
        for (int i = 0; i < 4; ++i)
#pragma unroll
            for (int r = 0; r < 4; ++r) {
                int rl = i * 16 + quad * 4 + r;       // 0..63 within wave rows
                red_m[w][rl] = m[i][r];
                red_s[w][rl] = s[i][r];
            }
    }
    float dv = dsum;
#pragma unroll
    for (int o = 1; o < 64; o <<= 1) dv += __shfl_xor(dv, o, 64);
    if (lane == 0) red_c[4 + w] = dv;
    __syncthreads();

    if (tid < 128) {
        int row = tid;                                // 0..127 local
        int wA = (row >> 6) * 2, rl = row & 63;
        float mA = red_m[wA][rl],     sA = red_s[wA][rl];
        float mB = red_m[wA + 1][rl], sB = red_s[wA + 1][rl];
        float mn = fmaxf(mA, mB);
        float ssum = sA * __expf(mA - mn) + sB * __expf(mB - mn);
        float contrib = mn + __logf(ssum);            // lse for this row
#pragma unroll
        for (int o = 1; o < 64; o <<= 1) contrib += __shfl_xor(contrib, o, 64);
        if (lane == 0) red_c[w] = contrib;
    }
    __syncthreads();
    if (tid == 0)
        atomicAdd(nce_acc, red_c[0] + red_c[1]
                  - (red_c[4] + red_c[5] + red_c[6] + red_c[7]));
}

// ---------------- tot29 = G[29] @ rep^T, full 3-pass split, LDS-free -------
__global__ __launch_bounds__(256) void tot29_kernel(
    const u16* __restrict__ Gh, const u16* __restrict__ Gl29,
    const u16* __restrict__ Rh, const u16* __restrict__ Rl,
    float* __restrict__ tot29)
{
    const int row0 = blockIdx.x * 128;
    const int col0 = blockIdx.y * 128;
    const int tid  = threadIdx.x;
    const int lane = tid & 63;
    const int w    = tid >> 6;
    const int ml   = lane & 15;
    const int quad = lane >> 4;
    const int wr   = (w >> 1) * 64;
    const int wc   = (w & 1) * 64;
    const u16* Gh29 = Gh + (size_t)(T_PRED - 1) * BN * DHH;

    f32x4 acc[4][4];
#pragma unroll
    for (int i = 0; i < 4; ++i)
#pragma unroll
        for (int j = 0; j < 4; ++j) acc[i][j] = (f32x4){0.f, 0.f, 0.f, 0.f};

#pragma unroll 1
    for (int kc = 0; kc < 4; ++kc) {
        short8 ah[4], al[4], bh[4], bl[4];
#pragma unroll
        for (int i = 0; i < 4; ++i) {
            size_t o = (size_t)(row0 + wr + i * 16 + ml) * DHH + kc * 32 + quad * 8;
            ah[i] = *(const short8*)(Gh29 + o);
            al[i] = *(const short8*)(Gl29 + o);
        }
#pragma unroll
        for (int j = 0; j < 4; ++j) {
            size_t o = (size_t)(col0 + wc + j * 16 + ml) * DHH + kc * 32 + quad * 8;
            bh[j] = *(const short8*)(Rh + o);
            bl[j] = *(const short8*)(Rl + o);
        }
#pragma unroll
        for (int i = 0; i < 4; ++i)
#pragma unroll
            for (int j = 0; j < 4; ++j) {
                acc[i][j] = __builtin_amdgcn_mfma_f32_16x16x32_bf16(ah[i], bh[j], acc[i][j], 0, 0, 0);
                acc[i][j] = __builtin_amdgcn_mfma_f32_16x16x32_bf16(ah[i], bl[j], acc[i][j], 0, 0, 0);
                acc[i][j] = __builtin_amdgcn_mfma_f32_16x16x32_bf16(al[i], bh[j], acc[i][j], 0, 0, 0);
            }
    }

#pragma unroll
    for (int i = 0; i < 4; ++i)
#pragma unroll
        for (int j = 0; j < 4; ++j)
#pragma unroll
            for (int r = 0; r < 4; ++r)
                tot29[(size_t)(row0 + wr + i * 16 + quad * 4 + r) * BN
                      + col0 + wc + j * 16 + ml] = acc[i][j][r];
}

// ---------------- lse29 per row + t=29 nce contribution --------------------
__global__ __launch_bounds__(256) void lse29_kernel(
    const float* __restrict__ tot29, float* __restrict__ lse29,
    float* __restrict__ nce_acc)
{
    __shared__ float part[4];
    const int lane = threadIdx.x & 63;
    const int wv   = threadIdx.x >> 6;
    const int row  = blockIdx.x * 4 + wv;
    const float* rp = tot29 + (size_t)row * BN;

    float mm = -3.0e38f, ss = 0.f;
#pragma unroll 1
    for (int p = 0; p < 8; ++p) {
        float4 v = *(const float4*)&rp[p * 256 + lane * 4];
        float tmax = fmaxf(fmaxf(v.x, v.y), fmaxf(v.z, v.w));
        float mn = fmaxf(mm, tmax);
        ss = ss * __expf(mm - mn) + __expf(v.x - mn) + __expf(v.y - mn)
                                  + __expf(v.z - mn) + __expf(v.w - mn);
        mm = mn;
    }
#pragma unroll
    for (int o = 1; o < 64; o <<= 1) {
        float mo2 = __shfl_xor(mm, o, 64);
        float so2 = __shfl_xor(ss, o, 64);
        float mn = fmaxf(mm, mo2);
        ss = ss * __expf(mm - mn) + so2 * __expf(mo2 - mn);
        mm = mn;
    }
    if (lane == 0) {
        float lse = mm + __logf(ss);
        lse29[row] = lse;
        part[wv] = lse - rp[row];           // lse - diag
    }
    __syncthreads();
    if (threadIdx.x == 0)
        atomicAdd(nce_acc, part[0] + part[1] + part[2] + part[3]);
}

// ---------------- argmax + count + final outputs (last-block pattern) ------
__device__ __forceinline__ u32 fenc(float f) {
    u32 u = __float_as_uint(f);
    return (u & 0x80000000u) ? ~u : (u | 0x80000000u);
}

__global__ __launch_bounds__(256) void argmax_fin_kernel(
    const float* __restrict__ tot29, const float* __restrict__ lse29,
    u64* __restrict__ table, u32* __restrict__ done,
    const float* __restrict__ nce_acc, float* __restrict__ out)
{
    __shared__ u32 lastflag;
    __shared__ int cpart[4];
    const int tid = threadIdx.x;
    const int c   = blockIdx.x * 256 + tid;
    const int b0  = blockIdx.y * 128;

    float best = -3.4e38f; int bi = 0;
    for (int b = b0; b < b0 + 128; ++b) {
        float v = tot29[(size_t)b * BN + c] - lse29[b];
        if (v > best) { best = v; bi = b; }
    }
    u64 key = ((u64)fenc(best) << 32) | (u32)(0xFFFFFFFFu - (u32)bi);
    atomicMax(table + c, key);

    __threadfence();
    if (tid == 0) lastflag = (atomicAdd(done, 1u) == 127u);
    __syncthreads();
    if (!lastflag) return;

    int cnt = 0;
    for (int i = tid; i < BN; i += 256) {
        u64 k = atomicAdd(table + i, 0ull);      // device-coherent read
        u32 b = 0xFFFFFFFFu - (u32)(k & 0xFFFFFFFFull);
        if ((int)b == i) cnt++;
    }
#pragma unroll
    for (int o = 1; o < 64; o <<= 1) cnt += __shfl_xor(cnt, o, 64);
    if ((tid & 63) == 0) cpart[tid >> 6] = cnt;
    __syncthreads();
    if (tid == 0) {
        int correct = cpart[0] + cpart[1] + cpart[2] + cpart[3];
        float nce = atomicAdd((float*)nce_acc, 0.0f);
        out[0] = (float)correct / (float)BN;
        out[1] = nce / (float)(BN * T_PRED);
        out[2] = (float)BN;
        out[3] = (float)(BN * T_PRED);
    }
}

extern "C" void kernel_launch(void* const* d_in, const int* in_sizes, int n_in,
                              void* d_out, int out_size, void* d_ws, size_t ws_size,
                              hipStream_t stream) {
    const float* E   = (const float*)d_in[0];   // [T,B,D]
    const float* rep = (const float*)d_in[1];   // [B,DH]
    const float* Ww  = (const float*)d_in[2];   // [T,D,DH]
    float* out = (float*)d_out;

    char* ws = (char*)d_ws;
    float* nce_acc = (float*)(ws + 0);
    u32*   done    = (u32*)(ws + 8);
    u64*   table   = (u64*)(ws + WS_TABLE);
    float* lse29   = (float*)(ws + WS_LSE);
    u16*   Wh      = (u16*)(ws + WS_WH);
    u16*   Wl      = (u16*)(ws + WS_WL);
    u16*   Rh      = (u16*)(ws + WS_RH);
    u16*   Rl      = (u16*)(ws + WS_RL);
    u16*   Gh      = (u16*)(ws + WS_GH);
    u16*   Gl29    = (u16*)(ws + WS_GL29);
    float* tot29   = (float*)(ws + WS_T29);

    hipMemsetAsync(ws, 0, 20480, stream);       // nce_acc, done, table
    prep_kernel<<<dim3(128), 256, 0, stream>>>(rep, Ww, Rh, Rl, Wh, Wl);
    g_kernel<<<dim3(16, 30), 256, 0, stream>>>(E, Wh, Wl, Gh, Gl29);
    nceA_kernel<<<dim3(16, 29), 256, 0, stream>>>(Gh, Rh, nce_acc);
    tot29_kernel<<<dim3(16, 16), 256, 0, stream>>>(Gh, Gl29, Rh, Rl, tot29);
    lse29_kernel<<<dim3(512), 256, 0, stream>>>(tot29, lse29, nce_acc);
    argmax_fin_kernel<<<dim3(8, 16), 256, 0, stream>>>(tot29, lse29, table, done,
                                                       nce_acc, out);
}